// Round 1
// baseline (727.535 us; speedup 1.0000x reference)
//
#include <hip/hip_runtime.h>

#define DIM 40
#define NSTEP 100

__device__ __forceinline__ void l96(const float* __restrict__ x, float* __restrict__ k) {
#pragma unroll
    for (int i = 0; i < DIM; ++i) {
        const int ip1 = (i + 1) % DIM;
        const int im2 = (i + DIM - 2) % DIM;
        const int im1 = (i + DIM - 1) % DIM;
        // (x_{i+1} - x_{i-2}) * x_{i-1} - x_i + F
        k[i] = fmaf(x[ip1] - x[im2], x[im1], 8.0f - x[i]);
    }
}

__global__ __launch_bounds__(256) void lorenz96_rk4_kernel(const float* __restrict__ in,
                                                           float* __restrict__ out,
                                                           int batch) {
    const int row = blockIdx.x * blockDim.x + threadIdx.x;
    if (row >= batch) return;

    const float4* __restrict__ src = (const float4*)(in + (size_t)row * DIM);
    float x[DIM];
#pragma unroll
    for (int i = 0; i < DIM / 4; ++i) {
        float4 v = src[i];
        x[4 * i + 0] = v.x;
        x[4 * i + 1] = v.y;
        x[4 * i + 2] = v.z;
        x[4 * i + 3] = v.w;
    }

    const float dt  = 0.01f;
    const float dt3 = dt * (1.0f / 3.0f);   // dt/3
    const float dt8 = dt * 0.125f;          // dt/8

#pragma unroll 1
    for (int s = 0; s < NSTEP; ++s) {
        float k1[DIM], k2[DIM], k3[DIM], a[DIM];

        // k1 = f(x)
        l96(x, k1);

        // k2 = f(x + dt*k1/3)
#pragma unroll
        for (int i = 0; i < DIM; ++i) a[i] = fmaf(dt3, k1[i], x[i]);
        l96(a, k2);

        // k3 = f(x + dt*(k2 - k1/3)) = f(x - dt/3*k1 + dt*k2)
#pragma unroll
        for (int i = 0; i < DIM; ++i) a[i] = fmaf(dt, k2[i], fmaf(-dt3, k1[i], x[i]));
        l96(a, k3);

        // k4 arg = x + dt*(k1 - k2 + k3); fold final sum k1 <- k1 + 3*(k2+k3)
#pragma unroll
        for (int i = 0; i < DIM; ++i) {
            float t = k2[i] + k3[i];
            float d = k1[i] + (k3[i] - k2[i]);
            a[i]  = fmaf(dt, d, x[i]);
            k1[i] = fmaf(3.0f, t, k1[i]);
        }
        // k4 = f(a), reuse k2 storage
        l96(a, k2);

        // x += dt/8 * (k1 + 3*(k2+k3) + k4)
#pragma unroll
        for (int i = 0; i < DIM; ++i) x[i] = fmaf(dt8, k1[i] + k2[i], x[i]);
    }

    float4* __restrict__ dst = (float4*)(out + (size_t)row * DIM);
#pragma unroll
    for (int i = 0; i < DIM / 4; ++i) {
        float4 v;
        v.x = x[4 * i + 0];
        v.y = x[4 * i + 1];
        v.z = x[4 * i + 2];
        v.w = x[4 * i + 3];
        dst[i] = v;
    }
}

extern "C" void kernel_launch(void* const* d_in, const int* in_sizes, int n_in,
                              void* d_out, int out_size, void* d_ws, size_t ws_size,
                              hipStream_t stream) {
    const float* x = (const float*)d_in[0];
    float* out = (float*)d_out;
    const int batch = in_sizes[0] / DIM;   // 262144
    const int block = 256;
    const int grid = (batch + block - 1) / block;
    lorenz96_rk4_kernel<<<grid, block, 0, stream>>>(x, out, batch);
}

// Round 2
// 613.490 us; speedup vs baseline: 1.1859x; 1.1859x over previous
//
#include <hip/hip_runtime.h>

#define DIM 40
#define NSTEP 100

// Out-of-place Lorenz96 RHS: k = (x_{i+1} - x_{i-2})*x_{i-1} - x_i + F
__device__ __forceinline__ void l96(const float* __restrict__ x, float* __restrict__ k) {
#pragma unroll
    for (int i = 0; i < DIM; ++i) {
        const int ip1 = (i + 1) % DIM;
        const int im2 = (i + DIM - 2) % DIM;
        const int im1 = (i + DIM - 1) % DIM;
        k[i] = fmaf(x[ip1] - x[im2], x[im1], 8.0f - x[i]);
    }
}

// In-place Lorenz96 RHS: a <- f(a). Rolling window keeps pre-overwrite
// neighbor values; under full unroll prev1/prev2 are pure SSA renames (free).
__device__ __forceinline__ void l96_inplace(float* a) {
    const float a0 = a[0];     // i=39 needs original a[0] as its +1 neighbor
    float prev2 = a[DIM - 2];  // original a[i-2]
    float prev1 = a[DIM - 1];  // original a[i-1]
#pragma unroll
    for (int i = 0; i < DIM; ++i) {
        const float ip1 = (i < DIM - 1) ? a[i + 1] : a0;
        const float old = a[i];
        a[i] = fmaf(ip1 - prev2, prev1, 8.0f - old);
        prev2 = prev1;
        prev1 = old;
    }
}

// Peak liveness: 4 arrays x 40 floats = 160 (phases 2-4), 120 after, 80 tail.
__global__ __launch_bounds__(256, 2) void lorenz96_rk4_kernel(const float* __restrict__ in,
                                                              float* __restrict__ out,
                                                              int batch) {
    const int row = blockIdx.x * blockDim.x + threadIdx.x;
    if (row >= batch) return;

    const float4* __restrict__ src = (const float4*)(in + (size_t)row * DIM);
    float X[DIM];  // x  -> b  -> a4 -> k4 -> x'
    float W[DIM];  // k1 -> u  -> a3 -> k3
    float A[DIM];  // acc
    float S[DIM];  // a2 -> k2
#pragma unroll
    for (int i = 0; i < DIM / 4; ++i) {
        float4 v = src[i];
        X[4 * i + 0] = v.x;
        X[4 * i + 1] = v.y;
        X[4 * i + 2] = v.z;
        X[4 * i + 3] = v.w;
    }

    const float dt  = 0.01f;
    const float dt3 = dt * (1.0f / 3.0f);  // dt/3
    const float dt8 = dt * 0.125f;         // dt/8
    const float th  = 3.0f * dt8;          // 3dt/8

#pragma unroll 1
    for (int s = 0; s < NSTEP; ++s) {
        // k1 = f(x)
        l96(X, W);

        // u = dt/3*k1 ; acc = x + dt/8*k1 = x + 0.375*u ; a2 = x + u
#pragma unroll
        for (int i = 0; i < DIM; ++i) {
            W[i] = dt3 * W[i];
            A[i] = fmaf(0.375f, W[i], X[i]);
            S[i] = X[i] + W[i];
        }

        // k2 = f(a2)   (in place: S)
        l96_inplace(S);

        // acc += 3dt/8*k2 ; a3 = (x - u) + dt*k2 ; b = (x + 3u) - dt*k2
        // after this X=b, W=a3, S(k2) dead, u dead, x dead
#pragma unroll
        for (int i = 0; i < DIM; ++i) {
            A[i] = fmaf(th, S[i], A[i]);
            const float t = X[i] - W[i];
            X[i] = fmaf(-dt, S[i], fmaf(3.0f, W[i], X[i]));  // b = x + dt*(k1 - k2)
            W[i] = fmaf(dt, S[i], t);                        // a3 = x + dt*(k2 - k1/3)
        }

        // k3 = f(a3)   (in place: W)
        l96_inplace(W);

        // acc += 3dt/8*k3 ; a4 = b + dt*k3 = x + dt*(k1 - k2 + k3)
#pragma unroll
        for (int i = 0; i < DIM; ++i) {
            A[i] = fmaf(th, W[i], A[i]);
            X[i] = fmaf(dt, W[i], X[i]);
        }

        // k4 = f(a4)   (in place: X)
        l96_inplace(X);

        // x' = acc + dt/8*k4
#pragma unroll
        for (int i = 0; i < DIM; ++i) X[i] = fmaf(dt8, X[i], A[i]);
    }

    float4* __restrict__ dst = (float4*)(out + (size_t)row * DIM);
#pragma unroll
    for (int i = 0; i < DIM / 4; ++i) {
        float4 v;
        v.x = X[4 * i + 0];
        v.y = X[4 * i + 1];
        v.z = X[4 * i + 2];
        v.w = X[4 * i + 3];
        dst[i] = v;
    }
}

extern "C" void kernel_launch(void* const* d_in, const int* in_sizes, int n_in,
                              void* d_out, int out_size, void* d_ws, size_t ws_size,
                              hipStream_t stream) {
    const float* x = (const float*)d_in[0];
    float* out = (float*)d_out;
    const int batch = in_sizes[0] / DIM;  // 262144
    const int block = 256;
    const int grid = (batch + block - 1) / block;
    lorenz96_rk4_kernel<<<grid, block, 0, stream>>>(x, out, batch);
}

// Round 3
// 602.081 us; speedup vs baseline: 1.2084x; 1.0189x over previous
//
#include <hip/hip_runtime.h>

#define DIM 40
#define NSTEP 100

// Out-of-place Lorenz96 RHS: k = (x_{i+1} - x_{i-2})*x_{i-1} - x_i + F
__device__ __forceinline__ void l96(const float* __restrict__ x, float* __restrict__ k) {
#pragma unroll
    for (int i = 0; i < DIM; ++i) {
        const int ip1 = (i + 1) % DIM;
        const int im2 = (i + DIM - 2) % DIM;
        const int im1 = (i + DIM - 1) % DIM;
        k[i] = fmaf(x[ip1] - x[im2], x[im1], 8.0f - x[i]);
    }
}

// In-place Lorenz96 RHS: a <- f(a). Rolling window keeps pre-overwrite
// neighbor values; under full unroll prev1/prev2 are pure SSA renames (free).
__device__ __forceinline__ void l96_inplace(float* a) {
    const float a0 = a[0];     // i=39 needs original a[0] as its +1 neighbor
    float prev2 = a[DIM - 2];  // original a[i-2]
    float prev1 = a[DIM - 1];  // original a[i-1]
#pragma unroll
    for (int i = 0; i < DIM; ++i) {
        const float ip1 = (i < DIM - 1) ? a[i + 1] : a0;
        const float old = a[i];
        a[i] = fmaf(ip1 - prev2, prev1, 8.0f - old);
        prev2 = prev1;
        prev1 = old;
    }
}

// Peak liveness ~170 floats (4x40 arrays + window temps + addressing).
// amdgpu_waves_per_eu(2,2): pin allocator's occupancy target to exactly
// 2 waves/EU -> 256-VGPR budget, no remat/spill. Round 2 showed the
// default heuristic shrinking this kernel to 72 VGPRs at a 1.8x VALU
// instruction bloat (43e9 vs 24e9 lane-ops).
__global__ void __launch_bounds__(256)
__attribute__((amdgpu_waves_per_eu(2, 2)))
lorenz96_rk4_kernel(const float* __restrict__ in,
                    float* __restrict__ out,
                    int batch) {
    const int row = blockIdx.x * blockDim.x + threadIdx.x;
    if (row >= batch) return;

    const float4* __restrict__ src = (const float4*)(in + (size_t)row * DIM);
    float X[DIM];  // x  -> b  -> a4 -> k4 -> x'
    float W[DIM];  // k1 -> u  -> a3 -> k3
    float A[DIM];  // acc
    float S[DIM];  // a2 -> k2
#pragma unroll
    for (int i = 0; i < DIM / 4; ++i) {
        float4 v = src[i];
        X[4 * i + 0] = v.x;
        X[4 * i + 1] = v.y;
        X[4 * i + 2] = v.z;
        X[4 * i + 3] = v.w;
    }

    const float dt  = 0.01f;
    const float dt3 = dt * (1.0f / 3.0f);  // dt/3
    const float dt8 = dt * 0.125f;         // dt/8
    const float th  = 3.0f * dt8;          // 3dt/8

#pragma unroll 1
    for (int s = 0; s < NSTEP; ++s) {
        // k1 = f(x)
        l96(X, W);

        // u = dt/3*k1 ; acc = x + dt/8*k1 = x + 0.375*u ; a2 = x + u
#pragma unroll
        for (int i = 0; i < DIM; ++i) {
            W[i] = dt3 * W[i];
            A[i] = fmaf(0.375f, W[i], X[i]);
            S[i] = X[i] + W[i];
        }

        // k2 = f(a2)   (in place: S)
        l96_inplace(S);

        // acc += 3dt/8*k2 ; a3 = (x - u) + dt*k2 ; b = (x + 3u) - dt*k2
        // after this X=b, W=a3, S(k2) dead, u dead, x dead
#pragma unroll
        for (int i = 0; i < DIM; ++i) {
            A[i] = fmaf(th, S[i], A[i]);
            const float t = X[i] - W[i];
            X[i] = fmaf(-dt, S[i], fmaf(3.0f, W[i], X[i]));  // b = x + dt*(k1 - k2)
            W[i] = fmaf(dt, S[i], t);                        // a3 = x + dt*(k2 - k1/3)
        }

        // k3 = f(a3)   (in place: W)
        l96_inplace(W);

        // acc += 3dt/8*k3 ; a4 = b + dt*k3 = x + dt*(k1 - k2 + k3)
#pragma unroll
        for (int i = 0; i < DIM; ++i) {
            A[i] = fmaf(th, W[i], A[i]);
            X[i] = fmaf(dt, W[i], X[i]);
        }

        // k4 = f(a4)   (in place: X)
        l96_inplace(X);

        // x' = acc + dt/8*k4
#pragma unroll
        for (int i = 0; i < DIM; ++i) X[i] = fmaf(dt8, X[i], A[i]);
    }

    float4* __restrict__ dst = (float4*)(out + (size_t)row * DIM);
#pragma unroll
    for (int i = 0; i < DIM / 4; ++i) {
        float4 v;
        v.x = X[4 * i + 0];
        v.y = X[4 * i + 1];
        v.z = X[4 * i + 2];
        v.w = X[4 * i + 3];
        dst[i] = v;
    }
}

extern "C" void kernel_launch(void* const* d_in, const int* in_sizes, int n_in,
                              void* d_out, int out_size, void* d_ws, size_t ws_size,
                              hipStream_t stream) {
    const float* x = (const float*)d_in[0];
    float* out = (float*)d_out;
    const int batch = in_sizes[0] / DIM;  // 262144
    const int block = 256;
    const int grid = (batch + block - 1) / block;
    lorenz96_rk4_kernel<<<grid, block, 0, stream>>>(x, out, batch);
}